// Round 4
// baseline (257.629 us; speedup 1.0000x reference)
//
#include <hip/hip_runtime.h>

// B=2048, N=64, D=256, H=16.
// out[b,n] = softmax_n( relu( ((N*u[b,n,:] - sum_n u) * item) @ W1 + b1 ) @ W2 )
// b2 dropped (softmax shift-invariant). y'[n,h]=(u[n,:]*item)@W1[:,h];
// z = 64*y' - sum_n y' + b1.
//
// Round-4: round-3 dataflow (1 wave/batch, lane=(n0,q), no in-loop barriers,
// xor-swizzled W1 in LDS, 128-B-line u reads) but the chunk loop is ROLLED
// (x4, two chunks/iter, explicit double buffer). Round-3's fully-unrolled
// body was ~40 KB > 32 KB L1I -> I$ streaming throttled issue (VALUBusy 15%,
// HBM 0.7 TB/s, LDS idle -- everything starved). ~10 KB body fits I$.
// Addresses strength-reduced: 6 base pointers bumped per iter, imm offsets.

static constexpr int NMEM = 64;
static constexpr int DDIM = 256;

__global__ __launch_bounds__(256) __attribute__((amdgpu_waves_per_eu(2, 2)))
void attn_group_softmax(const float* __restrict__ u_g,     // [B,64,256]
                        const float* __restrict__ item_g,  // [B,256]
                        const float* __restrict__ W1,      // [256,16]
                        const float* __restrict__ b1,      // [16]
                        const float* __restrict__ W2,      // [16,1]
                        float* __restrict__ out)           // [B,64]
{
    __shared__ __align__(16) float w1s[DDIM * 16];   // 16 KB, xor-swizzled

    const int tid  = threadIdx.x;
    const int w    = tid >> 6;
    const int lane = tid & 63;
    const int b    = blockIdx.x * 4 + w;      // one batch per wave

    // stage W1 swizzled: row d, logical float4 c at physical slot c^((d>>3)&3)
    {
        const int d = tid;
        const float4* src = (const float4*)(W1 + d * 16);
        float4*       dst = (float4*)w1s + d * 4;
        const int sw = (d >> 3) & 3;
        #pragma unroll
        for (int c = 0; c < 4; ++c) dst[c ^ sw] = src[c];
    }
    __syncthreads();   // the only barrier

    const int q  = lane & 3;
    const int n0 = lane >> 2;

    const float4* ug4  = (const float4*)u_g + (size_t)b * (NMEM * DDIM / 4);
    const float4* it4  = (const float4*)item_g + (size_t)b * (DDIM / 4);
    const float4* w1s4 = (const float4*)w1s;

    // base pointers; all in-loop loads use constant (imm) offsets
    const float4* p0 = ug4 + (n0 +  0) * 64 + 2 * q;
    const float4* p1 = ug4 + (n0 + 16) * 64 + 2 * q;
    const float4* p2 = ug4 + (n0 + 32) * 64 + 2 * q;
    const float4* p3 = ug4 + (n0 + 48) * 64 + 2 * q;
    const float4* pi = it4 + 2 * q;
    const float4* wp = w1s4 + 32 * q;         // row d=8q of chunk 0

    float acc[4][16];
    #pragma unroll
    for (int k = 0; k < 4; ++k)
        #pragma unroll
        for (int h = 0; h < 16; ++h) acc[k][h] = 0.f;

    float4 A[4][2], Bb[4][2], ia[2], ib[2];   // double-buffered chunk regs

    // y' partial over this lane's d-subset; one chunk = 32 d (lane owns 8)
    auto compute = [&](const float4 (&ubuf)[4][2], const float4 (&itb)[2],
                       const float4* wbase) {
        float s[4][8];
        #pragma unroll
        for (int k = 0; k < 4; ++k) {
            s[k][0] = ubuf[k][0].x * itb[0].x;
            s[k][1] = ubuf[k][0].y * itb[0].y;
            s[k][2] = ubuf[k][0].z * itb[0].z;
            s[k][3] = ubuf[k][0].w * itb[0].w;
            s[k][4] = ubuf[k][1].x * itb[1].x;
            s[k][5] = ubuf[k][1].y * itb[1].y;
            s[k][6] = ubuf[k][1].z * itb[1].z;
            s[k][7] = ubuf[k][1].w * itb[1].w;
        }
        #pragma unroll
        for (int e = 0; e < 8; ++e) {
            const float4* wrow = wbase + 4 * e;
            const float4 wv0 = wrow[0 ^ q];   // bank-conflict-free across q
            const float4 wv1 = wrow[1 ^ q];
            const float4 wv2 = wrow[2 ^ q];
            const float4 wv3 = wrow[3 ^ q];
            #pragma unroll
            for (int k = 0; k < 4; ++k) {
                const float sv = s[k][e];
                acc[k][ 0] = fmaf(sv, wv0.x, acc[k][ 0]);
                acc[k][ 1] = fmaf(sv, wv0.y, acc[k][ 1]);
                acc[k][ 2] = fmaf(sv, wv0.z, acc[k][ 2]);
                acc[k][ 3] = fmaf(sv, wv0.w, acc[k][ 3]);
                acc[k][ 4] = fmaf(sv, wv1.x, acc[k][ 4]);
                acc[k][ 5] = fmaf(sv, wv1.y, acc[k][ 5]);
                acc[k][ 6] = fmaf(sv, wv1.z, acc[k][ 6]);
                acc[k][ 7] = fmaf(sv, wv1.w, acc[k][ 7]);
                acc[k][ 8] = fmaf(sv, wv2.x, acc[k][ 8]);
                acc[k][ 9] = fmaf(sv, wv2.y, acc[k][ 9]);
                acc[k][10] = fmaf(sv, wv2.z, acc[k][10]);
                acc[k][11] = fmaf(sv, wv2.w, acc[k][11]);
                acc[k][12] = fmaf(sv, wv3.x, acc[k][12]);
                acc[k][13] = fmaf(sv, wv3.y, acc[k][13]);
                acc[k][14] = fmaf(sv, wv3.z, acc[k][14]);
                acc[k][15] = fmaf(sv, wv3.w, acc[k][15]);
            }
        }
    };

    // prefetch chunk 0 into A
    A[0][0] = p0[0]; A[0][1] = p0[1];
    A[1][0] = p1[0]; A[1][1] = p1[1];
    A[2][0] = p2[0]; A[2][1] = p2[1];
    A[3][0] = p3[0]; A[3][1] = p3[1];
    ia[0] = pi[0];   ia[1] = pi[1];

    #pragma unroll 1
    for (int mm = 0; mm < 8; mm += 2) {
        // prefetch chunk mm+1 into B (f4 offsets 8,9)
        Bb[0][0] = p0[8]; Bb[0][1] = p0[9];
        Bb[1][0] = p1[8]; Bb[1][1] = p1[9];
        Bb[2][0] = p2[8]; Bb[2][1] = p2[9];
        Bb[3][0] = p3[8]; Bb[3][1] = p3[9];
        ib[0] = pi[8];    ib[1] = pi[9];

        compute(A, ia, wp);                   // chunk mm

        if (mm < 6) {                         // prefetch chunk mm+2 into A
            A[0][0] = p0[16]; A[0][1] = p0[17];
            A[1][0] = p1[16]; A[1][1] = p1[17];
            A[2][0] = p2[16]; A[2][1] = p2[17];
            A[3][0] = p3[16]; A[3][1] = p3[17];
            ia[0] = pi[16];   ia[1] = pi[17];
        }

        compute(Bb, ib, wp + 128);            // chunk mm+1

        p0 += 16; p1 += 16; p2 += 16; p3 += 16; pi += 16;
        wp += 256;                            // 2 chunks * 128 f4
    }

    // ---- reduce partial d-sums over the 4 q-lanes (xor 1,2) ----
    #pragma unroll
    for (int k = 0; k < 4; ++k)
        #pragma unroll
        for (int h = 0; h < 16; ++h) {
            float v = acc[k][h];
            v += __shfl_xor(v, 1, 64);
            v += __shfl_xor(v, 2, 64);
            acc[k][h] = v;   // full y'[n0+16k][h], replicated across q
        }

    // ---- tt[h] = sum over all 64 members ----
    float tt[16];
    #pragma unroll
    for (int h = 0; h < 16; ++h) {
        float v = acc[0][h] + acc[1][h] + acc[2][h] + acc[3][h];
        #pragma unroll
        for (int off = 4; off <= 32; off <<= 1) v += __shfl_xor(v, off, 64);
        tt[h] = v;
    }

    // ---- b1 / W2 ----
    float b1c[16], w2c[16];
    {
        const float4* b4 = (const float4*)b1;
        const float4* w4 = (const float4*)W2;
        #pragma unroll
        for (int c = 0; c < 4; ++c) {
            const float4 t1 = b4[c], t2 = w4[c];
            b1c[4*c+0] = t1.x; b1c[4*c+1] = t1.y; b1c[4*c+2] = t1.z; b1c[4*c+3] = t1.w;
            w2c[4*c+0] = t2.x; w2c[4*c+1] = t2.y; w2c[4*c+2] = t2.z; w2c[4*c+3] = t2.w;
        }
    }

    // ---- logits: z = 64*y' - tt + b1, relu, dot W2 ----
    float p[4];
    #pragma unroll
    for (int k = 0; k < 4; ++k) {
        float sum = 0.f;
        #pragma unroll
        for (int h = 0; h < 16; ++h) {
            float z = fmaf(64.f, acc[k][h], b1c[h] - tt[h]);
            z = fmaxf(z, 0.f);
            sum = fmaf(z, w2c[h], sum);
        }
        p[k] = sum;
    }

    // ---- softmax over 64 members (16 n0-lanes x 4 rows, q-replicated) ----
    float m = fmaxf(fmaxf(p[0], p[1]), fmaxf(p[2], p[3]));
    #pragma unroll
    for (int off = 4; off <= 32; off <<= 1) m = fmaxf(m, __shfl_xor(m, off, 64));
    const float e0 = __expf(p[0] - m);
    const float e1 = __expf(p[1] - m);
    const float e2 = __expf(p[2] - m);
    const float e3 = __expf(p[3] - m);
    float sden = e0 + e1 + e2 + e3;
    #pragma unroll
    for (int off = 4; off <= 32; off <<= 1) sden += __shfl_xor(sden, off, 64);
    const float inv = 1.0f / sden;

    if (q == 0) {
        float* ob = out + (size_t)b * NMEM + n0;
        ob[0]  = e0 * inv;
        ob[16] = e1 * inv;
        ob[32] = e2 * inv;
        ob[48] = e3 * inv;
    }
}

extern "C" void kernel_launch(void* const* d_in, const int* in_sizes, int n_in,
                              void* d_out, int out_size, void* d_ws, size_t ws_size,
                              hipStream_t stream) {
    const float* u    = (const float*)d_in[0];  // members_embeds [2048,64,256]
    const float* item = (const float*)d_in[1];  // item_embeds   [2048,256]
    const float* W1   = (const float*)d_in[2];  // [256,16]
    const float* b1   = (const float*)d_in[3];  // [16]
    const float* W2   = (const float*)d_in[4];  // [16,1]
    // d_in[5] = b2: dropped (softmax shift-invariant)
    (void)in_sizes; (void)n_in; (void)out_size; (void)d_ws; (void)ws_size;

    attn_group_softmax<<<512, 256, 0, stream>>>(u, item, W1, b1, W2, (float*)d_out);
}